// Round 3
// baseline (1163.462 us; speedup 1.0000x reference)
//
#include <hip/hip_runtime.h>

#define D_MODEL 128
#define EDGE_DIM 16
#define TILE_N 32

__device__ __forceinline__ float gelu_exact(float x) {
    return 0.5f * x * (1.0f + erff(x * 0.70710678118654752440f));
}

// K1: build wT[256][128] (f32): wT[d][f] = W_src[f][d] (d<128), W_dst[f][d-128] (d>=128)
__global__ __launch_bounds__(256) void wt_kernel(
    const float* __restrict__ Wsrc, const float* __restrict__ Wdst,
    float* __restrict__ wT)
{
    int i = blockIdx.x * 256 + threadIdx.x;  // 0 .. 16383
    if (i < D_MODEL * D_MODEL) {
        int f = i & (D_MODEL - 1);
        int d = i >> 7;
        wT[d * D_MODEL + f]             = Wsrc[f * D_MODEL + d];
        wT[(d + D_MODEL) * D_MODEL + f] = Wdst[f * D_MODEL + d];
    }
}

// K2: per-edge gate MLP: gate[e] = sigmoid(gelu(ea @ w1^T + b1) @ w2^T + b2)
__global__ __launch_bounds__(256) void gate_kernel(
    const float* __restrict__ eattr,
    const float* __restrict__ gw1, const float* __restrict__ gb1,
    const float* __restrict__ gw2, const float* __restrict__ gb2,
    float* __restrict__ gate, int E)
{
    __shared__ float w1s[D_MODEL][EDGE_DIM];  // rows of gate_w1 (f32)
    __shared__ float b1s[D_MODEL];
    __shared__ float w2s[D_MODEL];
    int t = threadIdx.x;
    for (int i = t; i < D_MODEL * EDGE_DIM; i += 256)
        w1s[i >> 4][i & 15] = gw1[i];
    if (t < D_MODEL) { b1s[t] = gb1[t]; w2s[t] = gw2[t]; }
    __syncthreads();

    int e = blockIdx.x * 256 + t;
    if (e >= E) return;

    // 16 f32 = 64 B per edge, four 16B loads
    const float4* ear = (const float4*)(eattr + (size_t)e * EDGE_DIM);
    float4 e0 = ear[0], e1 = ear[1], e2 = ear[2], e3 = ear[3];
    float ea[16] = {e0.x, e0.y, e0.z, e0.w, e1.x, e1.y, e1.z, e1.w,
                    e2.x, e2.y, e2.z, e2.w, e3.x, e3.y, e3.z, e3.w};

    float acc = gb2[0];
#pragma unroll 4
    for (int j = 0; j < D_MODEL; j++) {
        const float4* wr = (const float4*)&w1s[j][0];
        float4 a = wr[0], b = wr[1], c = wr[2], d = wr[3];
        float hj = b1s[j];
        hj += ea[0]  * a.x + ea[1]  * a.y + ea[2]  * a.z + ea[3]  * a.w;
        hj += ea[4]  * b.x + ea[5]  * b.y + ea[6]  * b.z + ea[7]  * b.w;
        hj += ea[8]  * c.x + ea[9]  * c.y + ea[10] * c.z + ea[11] * c.w;
        hj += ea[12] * d.x + ea[13] * d.y + ea[14] * d.z + ea[15] * d.w;
        hj = gelu_exact(hj);
        acc += hj * w2s[j];
    }
    gate[e] = 1.0f / (1.0f + __expf(-acc));
}

// K3: scatter h[dst] += gate[e] * x_src[src], deg[dst] += 1. Two edges per wave.
__global__ __launch_bounds__(256) void scatter_kernel(
    const float* __restrict__ x_src,
    const int* __restrict__ esrc, const int* __restrict__ edst,
    const float* __restrict__ gate,
    float* __restrict__ h, float* __restrict__ deg, int E)
{
    int t = blockIdx.x * 256 + threadIdx.x;
    int lane = threadIdx.x & 63;
    int half = lane >> 5;   // which edge of the pair
    int li   = lane & 31;   // 4 elements per lane
    int wid = t >> 6;
    int nw  = (gridDim.x * 256) >> 6;

    for (int ep = wid; 2 * ep < E; ep += nw) {
        int e = 2 * ep + half;
        if (e >= E) continue;
        int s  = esrc[e];
        int dv = edst[e];
        float g = gate[e];
        const float4* xr = (const float4*)(x_src + (size_t)s * D_MODEL);
        float4 u = xr[li];
        float* hr = h + (size_t)dv * D_MODEL + li * 4;
        atomicAdd(hr + 0, g * u.x);
        atomicAdd(hr + 1, g * u.y);
        atomicAdd(hr + 2, g * u.z);
        atomicAdd(hr + 3, g * u.w);
        if (li == 0) atomicAdd(deg + dv, 1.0f);
    }
}

// K4: out[n] = gelu(LN( h[n]/max(deg,1) @ Wsrc^T + x_dst[n] @ Wdst^T + b ))
__global__ __launch_bounds__(256) void node_kernel(
    const float* __restrict__ h, const float* __restrict__ deg,
    const float* __restrict__ x_dst, const float* __restrict__ wT,
    const float* __restrict__ bdst, const float* __restrict__ gamma_,
    const float* __restrict__ beta_, float* __restrict__ out, int N)
{
    __shared__ float inT[256][TILE_N];      // 32 KB: transposed [d][n] inputs
    __shared__ float wtile[64 * D_MODEL];   // 32 KB: 64 rows of wT

    int t = threadIdx.x;
    int nb = blockIdx.x * TILE_N;

    // stage inputs transposed: d<128 -> h*rdeg, d>=128 -> x_dst
    {
        int nloc = t & 31;
        int dgrp = t >> 5;   // 0..7
        int n = nb + nloc;
        bool valid = n < N;
        float rdeg = 1.0f;
        if (valid) rdeg = 1.0f / fmaxf(deg[n], 1.0f);
        const float* hrow = h     + (size_t)n * D_MODEL;
        const float* xrow = x_dst + (size_t)n * D_MODEL;
#pragma unroll
        for (int r = 0; r < 8; r++) {
            int d = r * 32 + dgrp * 4;
            float4 v;
            if (r < 4) {
                if (valid) {
                    v = *(const float4*)(hrow + d);
                    v.x *= rdeg; v.y *= rdeg; v.z *= rdeg; v.w *= rdeg;
                } else v = make_float4(0.f, 0.f, 0.f, 0.f);
            } else {
                if (valid) {
                    v = *(const float4*)(xrow + (d - D_MODEL));
                } else v = make_float4(0.f, 0.f, 0.f, 0.f);
            }
            inT[d + 0][nloc] = v.x;
            inT[d + 1][nloc] = v.y;
            inT[d + 2][nloc] = v.z;
            inT[d + 3][nloc] = v.w;
        }
    }

    int f0 = (t & 31) * 4;   // 4 output cols
    int n0 = (t >> 5) * 4;   // 4 nodes
    float acc[4][4];
#pragma unroll
    for (int i = 0; i < 4; i++)
#pragma unroll
        for (int j = 0; j < 4; j++) acc[i][j] = 0.0f;

    for (int c = 0; c < 4; c++) {
        __syncthreads();  // also covers inT staging at c==0
#pragma unroll
        for (int i = 0; i < 8; i++) {
            int flat = i * 1024 + t * 4;
            *(float4*)&wtile[flat] = *(const float4*)&wT[c * 64 * D_MODEL + flat];
        }
        __syncthreads();
#pragma unroll 4
        for (int dd = 0; dd < 64; dd++) {
            int d = c * 64 + dd;
            float4 av = *(const float4*)&inT[d][n0];
            float4 wv = *(const float4*)&wtile[dd * D_MODEL + f0];
            acc[0][0] += av.x * wv.x; acc[0][1] += av.x * wv.y; acc[0][2] += av.x * wv.z; acc[0][3] += av.x * wv.w;
            acc[1][0] += av.y * wv.x; acc[1][1] += av.y * wv.y; acc[1][2] += av.y * wv.z; acc[1][3] += av.y * wv.w;
            acc[2][0] += av.z * wv.x; acc[2][1] += av.z * wv.y; acc[2][2] += av.z * wv.z; acc[2][3] += av.z * wv.w;
            acc[3][0] += av.w * wv.x; acc[3][1] += av.w * wv.y; acc[3][2] += av.w * wv.z; acc[3][3] += av.w * wv.w;
        }
    }

    // epilogue: + b_dst, LayerNorm over f, gelu, f32 store
    float4 bv = *(const float4*)(bdst + f0);
    float4 gv = *(const float4*)(gamma_ + f0);
    float4 ev = *(const float4*)(beta_ + f0);

#pragma unroll
    for (int i = 0; i < 4; i++) {
        acc[i][0] += bv.x; acc[i][1] += bv.y; acc[i][2] += bv.z; acc[i][3] += bv.w;
        float s1 = acc[i][0] + acc[i][1] + acc[i][2] + acc[i][3];
        float s2 = acc[i][0] * acc[i][0] + acc[i][1] * acc[i][1]
                 + acc[i][2] * acc[i][2] + acc[i][3] * acc[i][3];
#pragma unroll
        for (int m = 16; m >= 1; m >>= 1) {
            s1 += __shfl_xor(s1, m, 64);
            s2 += __shfl_xor(s2, m, 64);
        }
        float mu   = s1 * (1.0f / 128.0f);
        float var  = s2 * (1.0f / 128.0f) - mu * mu;
        float rstd = rsqrtf(var + 1e-5f);
        int n = nb + n0 + i;
        if (n < N) {
            float4 o;
            o.x = gelu_exact((acc[i][0] - mu) * rstd * gv.x + ev.x);
            o.y = gelu_exact((acc[i][1] - mu) * rstd * gv.y + ev.y);
            o.z = gelu_exact((acc[i][2] - mu) * rstd * gv.z + ev.z);
            o.w = gelu_exact((acc[i][3] - mu) * rstd * gv.w + ev.w);
            *(float4*)(out + (size_t)n * D_MODEL + f0) = o;
        }
    }
}

extern "C" void kernel_launch(void* const* d_in, const int* in_sizes, int n_in,
                              void* d_out, int out_size, void* d_ws, size_t ws_size,
                              hipStream_t stream) {
    const float* x_src  = (const float*)d_in[0];
    const float* x_dst  = (const float*)d_in[1];
    const int*   esrc   = (const int*)d_in[2];
    const int*   edst   = (const int*)d_in[3];
    const float* eattr  = (const float*)d_in[4];
    const float* Wsrc   = (const float*)d_in[5];
    const float* Wdst   = (const float*)d_in[6];
    const float* bdst   = (const float*)d_in[7];
    const float* gw1    = (const float*)d_in[8];
    const float* gb1    = (const float*)d_in[9];
    const float* gw2    = (const float*)d_in[10];
    const float* gb2    = (const float*)d_in[11];
    const float* gamma_ = (const float*)d_in[12];
    const float* beta_  = (const float*)d_in[13];
    float* out = (float*)d_out;

    int E = in_sizes[2];
    int N = in_sizes[1] / D_MODEL;

    // workspace layout (all f32): wT[256*128] | gate[E] | deg[N] | h[N*128]
    char* ws = (char*)d_ws;
    float* wT   = (float*)ws;
    size_t gateOff = (size_t)256 * D_MODEL * 4;                 // 131072
    float* gate = (float*)(ws + gateOff);
    size_t degOff = gateOff + (size_t)E * 4;
    degOff = (degOff + 255) & ~(size_t)255;
    float* deg = (float*)(ws + degOff);
    size_t hOff = degOff + (size_t)N * 4;
    hOff = (hOff + 255) & ~(size_t)255;
    float* h = (float*)(ws + hOff);

    // zero deg + h (contiguous region)
    hipMemsetAsync(ws + degOff, 0, (hOff - degOff) + (size_t)N * D_MODEL * 4, stream);

    wt_kernel<<<(D_MODEL * D_MODEL + 255) / 256, 256, 0, stream>>>(Wsrc, Wdst, wT);
    gate_kernel<<<(E + 255) / 256, 256, 0, stream>>>(eattr, gw1, gb1, gw2, gb2, gate, E);
    scatter_kernel<<<2048, 256, 0, stream>>>(x_src, esrc, edst, gate, h, deg, E);
    node_kernel<<<(N + TILE_N - 1) / TILE_N, 256, 0, stream>>>(
        h, deg, x_dst, wT, bdst, gamma_, beta_, out, N);
}

// Round 4
// 382.835 us; speedup vs baseline: 3.0391x; 3.0391x over previous
//
#include <hip/hip_runtime.h>

#define D_MODEL 128
#define EDGE_DIM 16
#define TILE_N 32

__device__ __forceinline__ float gelu_exact(float x) {
    return 0.5f * x * (1.0f + erff(x * 0.70710678118654752440f));
}

// K1: build wT[256][128] (f32): wT[d][f] = W_src[f][d] (d<128), W_dst[f][d-128] (d>=128)
__global__ __launch_bounds__(256) void wt_kernel(
    const float* __restrict__ Wsrc, const float* __restrict__ Wdst,
    float* __restrict__ wT)
{
    int i = blockIdx.x * 256 + threadIdx.x;  // 0 .. 16383
    if (i < D_MODEL * D_MODEL) {
        int f = i & (D_MODEL - 1);
        int d = i >> 7;
        wT[d * D_MODEL + f]             = Wsrc[f * D_MODEL + d];
        wT[(d + D_MODEL) * D_MODEL + f] = Wdst[f * D_MODEL + d];
    }
}

// K2: histogram of edge destinations
__global__ __launch_bounds__(256) void hist_kernel(
    const int* __restrict__ edst, int* __restrict__ degi, int E)
{
    int e = blockIdx.x * 256 + threadIdx.x;
    if (e < E) atomicAdd(&degi[edst[e]], 1);
}

// K3a: per-block exclusive scan of degi (256/block), block totals to partials
__global__ __launch_bounds__(256) void scan1_kernel(
    const int* __restrict__ degi, int* __restrict__ starts,
    int* __restrict__ partials, int N)
{
    __shared__ int sm[256];
    int t = threadIdx.x;
    int idx = blockIdx.x * 256 + t;
    int val = (idx < N) ? degi[idx] : 0;
    sm[t] = val;
    __syncthreads();
#pragma unroll
    for (int off = 1; off < 256; off <<= 1) {
        int x = (t >= off) ? sm[t - off] : 0;
        __syncthreads();
        sm[t] += x;
        __syncthreads();
    }
    if (idx < N) starts[idx] = sm[t] - val;       // exclusive within block
    if (t == 255) partials[blockIdx.x] = sm[255]; // block total
}

// K3b: exclusive scan of block partials (single block, nblocks <= 256)
__global__ __launch_bounds__(256) void scan2_kernel(
    int* __restrict__ partials, int nblocks)
{
    __shared__ int sm[256];
    int t = threadIdx.x;
    int val = (t < nblocks) ? partials[t] : 0;
    sm[t] = val;
    __syncthreads();
#pragma unroll
    for (int off = 1; off < 256; off <<= 1) {
        int x = (t >= off) ? sm[t - off] : 0;
        __syncthreads();
        sm[t] += x;
        __syncthreads();
    }
    if (t < nblocks) partials[t] = sm[t] - val;   // exclusive
}

// K3c: add block offsets; duplicate into cursor
__global__ __launch_bounds__(256) void scan3_kernel(
    int* __restrict__ starts, int* __restrict__ cursor,
    const int* __restrict__ partials, int N)
{
    int idx = blockIdx.x * 256 + threadIdx.x;
    if (idx < N) {
        int s = starts[idx] + partials[idx >> 8];
        starts[idx] = s;
        cursor[idx] = s;
    }
}

// K4: gate MLP fused with counting-sort scatter:
//   g = sigmoid(gelu(ea @ w1^T + b1) @ w2^T + b2); pos = cursor[dst]++;
//   sorted_src[pos] = esrc[e]; sorted_gate[pos] = g
__global__ __launch_bounds__(256) void gate_scatter_kernel(
    const float* __restrict__ eattr,
    const float* __restrict__ gw1, const float* __restrict__ gb1,
    const float* __restrict__ gw2, const float* __restrict__ gb2,
    const int* __restrict__ esrc, const int* __restrict__ edst,
    int* __restrict__ cursor,
    int* __restrict__ sorted_src, float* __restrict__ sorted_gate, int E)
{
    __shared__ float w1s[D_MODEL][EDGE_DIM];
    __shared__ float b1s[D_MODEL];
    __shared__ float w2s[D_MODEL];
    int t = threadIdx.x;
    for (int i = t; i < D_MODEL * EDGE_DIM; i += 256)
        w1s[i >> 4][i & 15] = gw1[i];
    if (t < D_MODEL) { b1s[t] = gb1[t]; w2s[t] = gw2[t]; }
    __syncthreads();

    int e = blockIdx.x * 256 + t;
    if (e >= E) return;

    const float4* ear = (const float4*)(eattr + (size_t)e * EDGE_DIM);
    float4 e0 = ear[0], e1 = ear[1], e2 = ear[2], e3 = ear[3];
    float ea[16] = {e0.x, e0.y, e0.z, e0.w, e1.x, e1.y, e1.z, e1.w,
                    e2.x, e2.y, e2.z, e2.w, e3.x, e3.y, e3.z, e3.w};

    float acc = gb2[0];
#pragma unroll 4
    for (int j = 0; j < D_MODEL; j++) {
        const float4* wr = (const float4*)&w1s[j][0];
        float4 a = wr[0], b = wr[1], c = wr[2], d = wr[3];
        float hj = b1s[j];
        hj += ea[0]  * a.x + ea[1]  * a.y + ea[2]  * a.z + ea[3]  * a.w;
        hj += ea[4]  * b.x + ea[5]  * b.y + ea[6]  * b.z + ea[7]  * b.w;
        hj += ea[8]  * c.x + ea[9]  * c.y + ea[10] * c.z + ea[11] * c.w;
        hj += ea[12] * d.x + ea[13] * d.y + ea[14] * d.z + ea[15] * d.w;
        hj = gelu_exact(hj);
        acc += hj * w2s[j];
    }
    float g = 1.0f / (1.0f + __expf(-acc));

    int dv = edst[e];
    int pos = atomicAdd(&cursor[dv], 1);
    sorted_src[pos]  = esrc[e];
    sorted_gate[pos] = g;
}

// K5: segmented aggregation, one wave per node, no atomics.
//   h[n] = (1/max(deg,1)) * sum_e gate[e] * x_src[src[e]]
__global__ __launch_bounds__(256) void agg_kernel(
    const float* __restrict__ x_src,
    const int* __restrict__ sorted_src, const float* __restrict__ sorted_gate,
    const int* __restrict__ starts, const int* __restrict__ degi,
    float* __restrict__ h, int N)
{
    int gid  = blockIdx.x * 256 + threadIdx.x;
    int n    = gid >> 6;        // one wave per node
    int li   = gid & 63;        // lane: dims 2li, 2li+1
    if (n >= N) return;

    int begin = starts[n];
    int cnt   = degi[n];

    float ax = 0.0f, ay = 0.0f;
    int s = 0; float g = 0.0f;
    if (cnt > 0) { s = sorted_src[begin]; g = sorted_gate[begin]; }
    for (int i = 0; i < cnt; i++) {
        int s2 = 0; float g2 = 0.0f;
        if (i + 1 < cnt) { s2 = sorted_src[begin + i + 1]; g2 = sorted_gate[begin + i + 1]; }
        const float2* xr = (const float2*)(x_src + (size_t)s * D_MODEL);
        float2 v = xr[li];
        ax += g * v.x;
        ay += g * v.y;
        s = s2; g = g2;
    }
    float r = 1.0f / (float)max(cnt, 1);
    float2 o; o.x = ax * r; o.y = ay * r;
    *(float2*)(h + (size_t)n * D_MODEL + li * 2) = o;
}

// K6: out[n] = gelu(LN( h[n] @ Wsrc^T + x_dst[n] @ Wdst^T + b ))   (h pre-normalized)
__global__ __launch_bounds__(256) void node_kernel(
    const float* __restrict__ h,
    const float* __restrict__ x_dst, const float* __restrict__ wT,
    const float* __restrict__ bdst, const float* __restrict__ gamma_,
    const float* __restrict__ beta_, float* __restrict__ out, int N)
{
    __shared__ float inT[256][TILE_N];      // 32 KB: transposed [d][n] inputs
    __shared__ float wtile[64 * D_MODEL];   // 32 KB: 64 rows of wT

    int t = threadIdx.x;
    int nb = blockIdx.x * TILE_N;

    // stage inputs transposed: d<128 -> h, d>=128 -> x_dst
    {
        int nloc = t & 31;
        int dgrp = t >> 5;   // 0..7
        int n = nb + nloc;
        bool valid = n < N;
        const float* hrow = h     + (size_t)n * D_MODEL;
        const float* xrow = x_dst + (size_t)n * D_MODEL;
#pragma unroll
        for (int r = 0; r < 8; r++) {
            int d = r * 32 + dgrp * 4;
            float4 v;
            if (r < 4) {
                v = valid ? *(const float4*)(hrow + d) : make_float4(0.f, 0.f, 0.f, 0.f);
            } else {
                v = valid ? *(const float4*)(xrow + (d - D_MODEL)) : make_float4(0.f, 0.f, 0.f, 0.f);
            }
            inT[d + 0][nloc] = v.x;
            inT[d + 1][nloc] = v.y;
            inT[d + 2][nloc] = v.z;
            inT[d + 3][nloc] = v.w;
        }
    }

    int f0 = (t & 31) * 4;   // 4 output cols
    int n0 = (t >> 5) * 4;   // 4 nodes
    float acc[4][4];
#pragma unroll
    for (int i = 0; i < 4; i++)
#pragma unroll
        for (int j = 0; j < 4; j++) acc[i][j] = 0.0f;

    for (int c = 0; c < 4; c++) {
        __syncthreads();  // also covers inT staging at c==0
#pragma unroll
        for (int i = 0; i < 8; i++) {
            int flat = i * 1024 + t * 4;
            *(float4*)&wtile[flat] = *(const float4*)&wT[c * 64 * D_MODEL + flat];
        }
        __syncthreads();
#pragma unroll 4
        for (int dd = 0; dd < 64; dd++) {
            int d = c * 64 + dd;
            float4 av = *(const float4*)&inT[d][n0];
            float4 wv = *(const float4*)&wtile[dd * D_MODEL + f0];
            acc[0][0] += av.x * wv.x; acc[0][1] += av.x * wv.y; acc[0][2] += av.x * wv.z; acc[0][3] += av.x * wv.w;
            acc[1][0] += av.y * wv.x; acc[1][1] += av.y * wv.y; acc[1][2] += av.y * wv.z; acc[1][3] += av.y * wv.w;
            acc[2][0] += av.z * wv.x; acc[2][1] += av.z * wv.y; acc[2][2] += av.z * wv.z; acc[2][3] += av.z * wv.w;
            acc[3][0] += av.w * wv.x; acc[3][1] += av.w * wv.y; acc[3][2] += av.w * wv.z; acc[3][3] += av.w * wv.w;
        }
    }

    // epilogue: + b_dst, LayerNorm over f, gelu, f32 store
    float4 bv = *(const float4*)(bdst + f0);
    float4 gv = *(const float4*)(gamma_ + f0);
    float4 ev = *(const float4*)(beta_ + f0);

#pragma unroll
    for (int i = 0; i < 4; i++) {
        acc[i][0] += bv.x; acc[i][1] += bv.y; acc[i][2] += bv.z; acc[i][3] += bv.w;
        float s1 = acc[i][0] + acc[i][1] + acc[i][2] + acc[i][3];
        float s2 = acc[i][0] * acc[i][0] + acc[i][1] * acc[i][1]
                 + acc[i][2] * acc[i][2] + acc[i][3] * acc[i][3];
#pragma unroll
        for (int m = 16; m >= 1; m >>= 1) {
            s1 += __shfl_xor(s1, m, 64);
            s2 += __shfl_xor(s2, m, 64);
        }
        float mu   = s1 * (1.0f / 128.0f);
        float var  = s2 * (1.0f / 128.0f) - mu * mu;
        float rstd = rsqrtf(var + 1e-5f);
        int n = nb + n0 + i;
        if (n < N) {
            float4 o;
            o.x = gelu_exact((acc[i][0] - mu) * rstd * gv.x + ev.x);
            o.y = gelu_exact((acc[i][1] - mu) * rstd * gv.y + ev.y);
            o.z = gelu_exact((acc[i][2] - mu) * rstd * gv.z + ev.z);
            o.w = gelu_exact((acc[i][3] - mu) * rstd * gv.w + ev.w);
            *(float4*)(out + (size_t)n * D_MODEL + f0) = o;
        }
    }
}

extern "C" void kernel_launch(void* const* d_in, const int* in_sizes, int n_in,
                              void* d_out, int out_size, void* d_ws, size_t ws_size,
                              hipStream_t stream) {
    const float* x_src  = (const float*)d_in[0];
    const float* x_dst  = (const float*)d_in[1];
    const int*   esrc   = (const int*)d_in[2];
    const int*   edst   = (const int*)d_in[3];
    const float* eattr  = (const float*)d_in[4];
    const float* Wsrc   = (const float*)d_in[5];
    const float* Wdst   = (const float*)d_in[6];
    const float* bdst   = (const float*)d_in[7];
    const float* gw1    = (const float*)d_in[8];
    const float* gb1    = (const float*)d_in[9];
    const float* gw2    = (const float*)d_in[10];
    const float* gb2    = (const float*)d_in[11];
    const float* gamma_ = (const float*)d_in[12];
    const float* beta_  = (const float*)d_in[13];
    float* out = (float*)d_out;

    int E = in_sizes[2];
    int N = in_sizes[1] / D_MODEL;

    // workspace layout (bump-allocated, 256B aligned):
    char* ws = (char*)d_ws;
    size_t off = 0;
    auto alloc = [&](size_t bytes) {
        size_t cur = off;
        off = (off + bytes + 255) & ~(size_t)255;
        return (void*)(ws + cur);
    };
    float* wT          = (float*)alloc((size_t)256 * D_MODEL * 4);
    int*   degi        = (int*)  alloc((size_t)N * 4);
    int*   starts      = (int*)  alloc((size_t)N * 4);
    int*   cursor      = (int*)  alloc((size_t)N * 4);
    int*   partials    = (int*)  alloc(256 * 4);
    int*   sorted_src  = (int*)  alloc((size_t)E * 4);
    float* sorted_gate = (float*)alloc((size_t)E * 4);
    float* h           = (float*)alloc((size_t)N * D_MODEL * 4);

    int nblocksN = (N + 255) / 256;   // 196 for N=50000 (<=256 required by scan2)
    int nblocksE = (E + 255) / 256;

    hipMemsetAsync(degi, 0, (size_t)N * 4, stream);

    wt_kernel<<<(D_MODEL * D_MODEL + 255) / 256, 256, 0, stream>>>(Wsrc, Wdst, wT);
    hist_kernel<<<nblocksE, 256, 0, stream>>>(edst, degi, E);
    scan1_kernel<<<nblocksN, 256, 0, stream>>>(degi, starts, partials, N);
    scan2_kernel<<<1, 256, 0, stream>>>(partials, nblocksN);
    scan3_kernel<<<nblocksN, 256, 0, stream>>>(starts, cursor, partials, N);
    gate_scatter_kernel<<<nblocksE, 256, 0, stream>>>(
        eattr, gw1, gb1, gw2, gb2, esrc, edst, cursor, sorted_src, sorted_gate, E);
    agg_kernel<<<(N * 64 + 255) / 256, 256, 0, stream>>>(
        x_src, sorted_src, sorted_gate, starts, degi, h, N);
    node_kernel<<<(N + TILE_N - 1) / TILE_N, 256, 0, stream>>>(
        h, x_dst, wT, bdst, gamma_, beta_, out, N);
}

// Round 5
// 357.775 us; speedup vs baseline: 3.2519x; 1.0700x over previous
//
#include <hip/hip_runtime.h>

#define D_MODEL 128
#define EDGE_DIM 16

// Fast erf (Winitzki): max abs error ~1.25e-4, branchless.
__device__ __forceinline__ float erf_fast(float z) {
    float z2  = z * z;
    float num = fmaf(0.147f, z2, 1.27323954f);   // 4/pi + a*z^2
    float den = fmaf(0.147f, z2, 1.0f);          // 1 + a*z^2
    float r   = num * __builtin_amdgcn_rcpf(den);
    float e   = __expf(-z2 * r);
    float y   = __builtin_amdgcn_sqrtf(fmaxf(1.0f - e, 0.0f));
    return copysignf(y, z);
}

__device__ __forceinline__ float gelu_fast(float x) {
    return 0.5f * x * (1.0f + erf_fast(x * 0.70710678118654752440f));
}

// K1: build wT[256][128] (f32): wT[d][f] = W_src[f][d] (d<128), W_dst[f][d-128] (d>=128)
__global__ __launch_bounds__(256) void wt_kernel(
    const float* __restrict__ Wsrc, const float* __restrict__ Wdst,
    float* __restrict__ wT)
{
    int i = blockIdx.x * 256 + threadIdx.x;  // 0 .. 16383
    if (i < D_MODEL * D_MODEL) {
        int f = i & (D_MODEL - 1);
        int d = i >> 7;
        wT[d * D_MODEL + f]             = Wsrc[f * D_MODEL + d];
        wT[(d + D_MODEL) * D_MODEL + f] = Wdst[f * D_MODEL + d];
    }
}

// K2: histogram of edge destinations
__global__ __launch_bounds__(256) void hist_kernel(
    const int* __restrict__ edst, int* __restrict__ degi, int E)
{
    int e = blockIdx.x * 256 + threadIdx.x;
    if (e < E) atomicAdd(&degi[edst[e]], 1);
}

// K3a: per-block exclusive scan of degi (256/block), block totals to partials
__global__ __launch_bounds__(256) void scan1_kernel(
    const int* __restrict__ degi, int* __restrict__ starts,
    int* __restrict__ partials, int N)
{
    __shared__ int sm[256];
    int t = threadIdx.x;
    int idx = blockIdx.x * 256 + t;
    int val = (idx < N) ? degi[idx] : 0;
    sm[t] = val;
    __syncthreads();
#pragma unroll
    for (int off = 1; off < 256; off <<= 1) {
        int x = (t >= off) ? sm[t - off] : 0;
        __syncthreads();
        sm[t] += x;
        __syncthreads();
    }
    if (idx < N) starts[idx] = sm[t] - val;       // exclusive within block
    if (t == 255) partials[blockIdx.x] = sm[255]; // block total
}

// K3b: exclusive scan of block partials (single block, nblocks <= 256)
__global__ __launch_bounds__(256) void scan2_kernel(
    int* __restrict__ partials, int nblocks)
{
    __shared__ int sm[256];
    int t = threadIdx.x;
    int val = (t < nblocks) ? partials[t] : 0;
    sm[t] = val;
    __syncthreads();
#pragma unroll
    for (int off = 1; off < 256; off <<= 1) {
        int x = (t >= off) ? sm[t - off] : 0;
        __syncthreads();
        sm[t] += x;
        __syncthreads();
    }
    if (t < nblocks) partials[t] = sm[t] - val;   // exclusive
}

// K3c: add block offsets; duplicate into cursor
__global__ __launch_bounds__(256) void scan3_kernel(
    int* __restrict__ starts, int* __restrict__ cursor,
    const int* __restrict__ partials, int N)
{
    int idx = blockIdx.x * 256 + threadIdx.x;
    if (idx < N) {
        int s = starts[idx] + partials[idx >> 8];
        starts[idx] = s;
        cursor[idx] = s;
    }
}

// K4: gate MLP fused with counting-sort scatter
__global__ __launch_bounds__(256) void gate_scatter_kernel(
    const float* __restrict__ eattr,
    const float* __restrict__ gw1, const float* __restrict__ gb1,
    const float* __restrict__ gw2, const float* __restrict__ gb2,
    const int* __restrict__ esrc, const int* __restrict__ edst,
    int* __restrict__ cursor,
    int* __restrict__ sorted_src, float* __restrict__ sorted_gate, int E)
{
    __shared__ float w1s[D_MODEL][EDGE_DIM];
    __shared__ float b1s[D_MODEL];
    __shared__ float w2s[D_MODEL];
    int t = threadIdx.x;
    for (int i = t; i < D_MODEL * EDGE_DIM; i += 256)
        w1s[i >> 4][i & 15] = gw1[i];
    if (t < D_MODEL) { b1s[t] = gb1[t]; w2s[t] = gw2[t]; }
    __syncthreads();

    int e = blockIdx.x * 256 + t;
    if (e >= E) return;

    const float4* ear = (const float4*)(eattr + (size_t)e * EDGE_DIM);
    float4 e0 = ear[0], e1 = ear[1], e2 = ear[2], e3 = ear[3];
    float ea[16] = {e0.x, e0.y, e0.z, e0.w, e1.x, e1.y, e1.z, e1.w,
                    e2.x, e2.y, e2.z, e2.w, e3.x, e3.y, e3.z, e3.w};

    float acc = gb2[0];
#pragma unroll 4
    for (int j = 0; j < D_MODEL; j++) {
        const float4* wr = (const float4*)&w1s[j][0];
        float4 a = wr[0], b = wr[1], c = wr[2], d = wr[3];
        float hj = b1s[j];
        hj += ea[0]  * a.x + ea[1]  * a.y + ea[2]  * a.z + ea[3]  * a.w;
        hj += ea[4]  * b.x + ea[5]  * b.y + ea[6]  * b.z + ea[7]  * b.w;
        hj += ea[8]  * c.x + ea[9]  * c.y + ea[10] * c.z + ea[11] * c.w;
        hj += ea[12] * d.x + ea[13] * d.y + ea[14] * d.z + ea[15] * d.w;
        hj = gelu_fast(hj);
        acc += hj * w2s[j];
    }
    float g = 1.0f / (1.0f + __expf(-acc));

    int dv = edst[e];
    int pos = atomicAdd(&cursor[dv], 1);
    sorted_src[pos]  = esrc[e];
    sorted_gate[pos] = g;
}

// K5: segmented aggregation, one wave per node, no atomics, 2-edge unrolled.
__global__ __launch_bounds__(256) void agg_kernel(
    const float* __restrict__ x_src,
    const int* __restrict__ sorted_src, const float* __restrict__ sorted_gate,
    const int* __restrict__ starts, const int* __restrict__ degi,
    float* __restrict__ h, int N)
{
    int gid  = blockIdx.x * 256 + threadIdx.x;
    int n    = gid >> 6;        // one wave per node
    int li   = gid & 63;        // lane: dims 2li, 2li+1
    if (n >= N) return;

    int begin = starts[n];
    int cnt   = degi[n];

    float ax = 0.0f, ay = 0.0f;
    int i = 0;
    for (; i + 2 <= cnt; i += 2) {
        int   sA = sorted_src[begin + i];
        int   sB = sorted_src[begin + i + 1];
        float gA = sorted_gate[begin + i];
        float gB = sorted_gate[begin + i + 1];
        float2 vA = ((const float2*)(x_src + (size_t)sA * D_MODEL))[li];
        float2 vB = ((const float2*)(x_src + (size_t)sB * D_MODEL))[li];
        ax += gA * vA.x + gB * vB.x;
        ay += gA * vA.y + gB * vB.y;
    }
    if (i < cnt) {
        int   s = sorted_src[begin + i];
        float g = sorted_gate[begin + i];
        float2 v = ((const float2*)(x_src + (size_t)s * D_MODEL))[li];
        ax += g * v.x;
        ay += g * v.y;
    }
    float r = 1.0f / (float)max(cnt, 1);
    float2 o; o.x = ax * r; o.y = ay * r;
    *(float2*)(h + (size_t)n * D_MODEL + li * 2) = o;
}

// K6: out[n] = gelu(LN( [h | x_dst] @ wT + b )), 128-node x 128-f tile,
// per-thread 8x8 accumulator in split {base, base+64} layout.
#define NT   128   // nodes per block
#define KC    32   // k-chunk
#define IPAD 132   // inT row stride (floats)

__global__ __launch_bounds__(256) void node_kernel(
    const float* __restrict__ h,
    const float* __restrict__ x_dst, const float* __restrict__ wT,
    const float* __restrict__ bdst, const float* __restrict__ gamma_,
    const float* __restrict__ beta_, float* __restrict__ out, int N)
{
    __shared__ float inT[KC][IPAD];      // [k][n], 16.9 KB
    __shared__ float wt_s[KC][D_MODEL];  // [k][f], 16 KB

    int t  = threadIdx.x;
    int nb = blockIdx.x * NT;
    int fg = t & 15;           // f-group: f in {fg*4..+3} U {fg*4+64..+3}
    int ng = t >> 4;           // n-group: n in {ng*4..+3} U {ng*4+64..+3}
    int f0 = fg * 4;
    int n0 = ng * 4;

    float acc[8][8];
#pragma unroll
    for (int i = 0; i < 8; i++)
#pragma unroll
        for (int j = 0; j < 8; j++) acc[i][j] = 0.0f;

    for (int c = 0; c < 8; c++) {        // 8 chunks of KC=32 over K=256
        int kb = c * KC;
        const float* src = (kb < D_MODEL) ? h : x_dst;
        int koff = kb & (D_MODEL - 1);
        __syncthreads();
        // stage weights: 32 rows x 128 f = 1024 float4, 4 per thread
#pragma unroll
        for (int i = 0; i < 4; i++) {
            int flat = i * 256 + t;          // 0..1023
            int kr = flat >> 5;              // 0..31
            int cc = flat & 31;              // float4 within row
            *(float4*)&wt_s[kr][cc * 4] =
                *(const float4*)&wT[(size_t)(kb + kr) * D_MODEL + cc * 4];
        }
        // stage inputs transposed: 128 rows(n) x 8 float4(k)
#pragma unroll
        for (int i = 0; i < 4; i++) {
            int flat = i * 256 + t;          // 0..1023
            int n  = flat >> 3;              // 0..127
            int cc = flat & 7;               // float4 within 32-k chunk
            int gn = nb + n;
            float4 v = make_float4(0.f, 0.f, 0.f, 0.f);
            if (gn < N) v = *(const float4*)&src[(size_t)gn * D_MODEL + koff + cc * 4];
            inT[cc * 4 + 0][n] = v.x;
            inT[cc * 4 + 1][n] = v.y;
            inT[cc * 4 + 2][n] = v.z;
            inT[cc * 4 + 3][n] = v.w;
        }
        __syncthreads();
#pragma unroll 4
        for (int k = 0; k < KC; k++) {
            float4 a0 = *(const float4*)&inT[k][n0];
            float4 a1 = *(const float4*)&inT[k][n0 + 64];
            float4 w0 = *(const float4*)&wt_s[k][f0];
            float4 w1 = *(const float4*)&wt_s[k][f0 + 64];
            float av[8] = {a0.x, a0.y, a0.z, a0.w, a1.x, a1.y, a1.z, a1.w};
            float wv[8] = {w0.x, w0.y, w0.z, w0.w, w1.x, w1.y, w1.z, w1.w};
#pragma unroll
            for (int i = 0; i < 8; i++)
#pragma unroll
                for (int j = 0; j < 8; j++)
                    acc[i][j] = fmaf(av[i], wv[j], acc[i][j]);
        }
    }

    // epilogue: + b, LayerNorm over f (128 vals across 16 lanes x 8 regs), gelu, store
    float4 b0 = *(const float4*)(bdst + f0);
    float4 b1 = *(const float4*)(bdst + f0 + 64);
    float4 g0 = *(const float4*)(gamma_ + f0);
    float4 g1 = *(const float4*)(gamma_ + f0 + 64);
    float4 e0 = *(const float4*)(beta_ + f0);
    float4 e1 = *(const float4*)(beta_ + f0 + 64);
    float bv[8] = {b0.x, b0.y, b0.z, b0.w, b1.x, b1.y, b1.z, b1.w};
    float gv[8] = {g0.x, g0.y, g0.z, g0.w, g1.x, g1.y, g1.z, g1.w};
    float ev[8] = {e0.x, e0.y, e0.z, e0.w, e1.x, e1.y, e1.z, e1.w};

#pragma unroll
    for (int i = 0; i < 8; i++) {
        float s1 = 0.0f, s2 = 0.0f;
#pragma unroll
        for (int j = 0; j < 8; j++) {
            acc[i][j] += bv[j];
            s1 += acc[i][j];
            s2 += acc[i][j] * acc[i][j];
        }
        // reduce across the 16-lane f-group (masks 1,2,4,8 stay inside it)
#pragma unroll
        for (int m = 8; m >= 1; m >>= 1) {
            s1 += __shfl_xor(s1, m, 64);
            s2 += __shfl_xor(s2, m, 64);
        }
        float mu   = s1 * (1.0f / 128.0f);
        float var  = s2 * (1.0f / 128.0f) - mu * mu;
        float rstd = rsqrtf(var + 1e-5f);
        int n = nb + n0 + ((i < 4) ? i : (60 + i));   // i>=4 -> n0 + 64 + (i-4)
        if (n < N) {
            float y[8];
#pragma unroll
            for (int j = 0; j < 8; j++)
                y[j] = gelu_fast((acc[i][j] - mu) * rstd * gv[j] + ev[j]);
            float4 o0 = make_float4(y[0], y[1], y[2], y[3]);
            float4 o1 = make_float4(y[4], y[5], y[6], y[7]);
            *(float4*)(out + (size_t)n * D_MODEL + f0)      = o0;
            *(float4*)(out + (size_t)n * D_MODEL + f0 + 64) = o1;
        }
    }
}

extern "C" void kernel_launch(void* const* d_in, const int* in_sizes, int n_in,
                              void* d_out, int out_size, void* d_ws, size_t ws_size,
                              hipStream_t stream) {
    const float* x_src  = (const float*)d_in[0];
    const float* x_dst  = (const float*)d_in[1];
    const int*   esrc   = (const int*)d_in[2];
    const int*   edst   = (const int*)d_in[3];
    const float* eattr  = (const float*)d_in[4];
    const float* Wsrc   = (const float*)d_in[5];
    const float* Wdst   = (const float*)d_in[6];
    const float* bdst   = (const float*)d_in[7];
    const float* gw1    = (const float*)d_in[8];
    const float* gb1    = (const float*)d_in[9];
    const float* gw2    = (const float*)d_in[10];
    const float* gb2    = (const float*)d_in[11];
    const float* gamma_ = (const float*)d_in[12];
    const float* beta_  = (const float*)d_in[13];
    float* out = (float*)d_out;

    int E = in_sizes[2];
    int N = in_sizes[1] / D_MODEL;

    // workspace layout (bump-allocated, 256B aligned):
    char* ws = (char*)d_ws;
    size_t off = 0;
    auto alloc = [&](size_t bytes) {
        size_t cur = off;
        off = (off + bytes + 255) & ~(size_t)255;
        return (void*)(ws + cur);
    };
    float* wT          = (float*)alloc((size_t)256 * D_MODEL * 4);
    int*   degi        = (int*)  alloc((size_t)N * 4);
    int*   starts      = (int*)  alloc((size_t)N * 4);
    int*   cursor      = (int*)  alloc((size_t)N * 4);
    int*   partials    = (int*)  alloc(256 * 4);
    int*   sorted_src  = (int*)  alloc((size_t)E * 4);
    float* sorted_gate = (float*)alloc((size_t)E * 4);
    float* h           = (float*)alloc((size_t)N * D_MODEL * 4);

    int nblocksN = (N + 255) / 256;   // 196 for N=50000 (<=256 required by scan2)
    int nblocksE = (E + 255) / 256;

    hipMemsetAsync(degi, 0, (size_t)N * 4, stream);

    wt_kernel<<<(D_MODEL * D_MODEL + 255) / 256, 256, 0, stream>>>(Wsrc, Wdst, wT);
    hist_kernel<<<nblocksE, 256, 0, stream>>>(edst, degi, E);
    scan1_kernel<<<nblocksN, 256, 0, stream>>>(degi, starts, partials, N);
    scan2_kernel<<<1, 256, 0, stream>>>(partials, nblocksN);
    scan3_kernel<<<nblocksN, 256, 0, stream>>>(starts, cursor, partials, N);
    gate_scatter_kernel<<<nblocksE, 256, 0, stream>>>(
        eattr, gw1, gb1, gw2, gb2, esrc, edst, cursor, sorted_src, sorted_gate, E);
    agg_kernel<<<(N * 64 + 255) / 256, 256, 0, stream>>>(
        x_src, sorted_src, sorted_gate, starts, degi, h, N);
    node_kernel<<<(N + NT - 1) / NT, 256, 0, stream>>>(
        h, x_dst, wT, bdst, gamma_, beta_, out, N);
}